// Round 7
// baseline (380.635 us; speedup 1.0000x reference)
//
#include <hip/hip_runtime.h>

#define BATCH 256
#define TT 4096
#define NS 32
#define NI 8
#define NO 8
#define LCH 64
#define NCHUNKS 64  // TT / LCH

// ws layout (floats)
#define WS_M  0
#define WS_N0 1024
#define WS_N1 1280
#define WS_ML 1536
#define WS_V  2560
#define WS_S  (2560 + BATCH * NCHUNKS * NS)
#define WS_F  (WS_S + BATCH * NCHUNKS * NS)  // [LCH+1][NS][NI]

__device__ __forceinline__ float dot4(float4 a, float4 b) {
    return a.x * b.x + a.y * b.y + a.z * b.z + a.w * b.w;
}
__device__ __forceinline__ float4 ld4(const float* p) { return *(const float4*)p; }

// ---------------------------------------------------------------------------
// Kernel 0: build step matrices M, N0, N1 (one Dopri5 step == x' = M x + N0 u0 + N1 u1),
// ML = M^64, and convolution kernels F_j (v[b][c] = sum_j F_j u_{t0+j}).
// F build is log-depth: F_j = M^(63-j) H with H = N0' + M N1'; M^8 captured
// during the ML squarings; 7 serial seed steps + 7 parallel 8-chain steps.
// ---------------------------------------------------------------------------
__global__ __launch_bounds__(256) void k_pre(const float* __restrict__ tarr,
                                             const float* __restrict__ A,
                                             const float* __restrict__ B,
                                             float* __restrict__ ws) {
    __shared__ float sA[NS * NS], sB[NS * NI];
    __shared__ float Ka[6][NS * NS];
    __shared__ float Kb[6][NS * NI];
    __shared__ float Kc[6][NS * NI];
    __shared__ float Sa[NS * NS], Sb[NS * NI], Sc[NS * NI];
    __shared__ float Pq[2][NS * NS];
    __shared__ float Ms[NS * NS];

    const int tid = threadIdx.x;
    const float dt = tarr[1] - tarr[0];

    for (int e = tid; e < NS * NS; e += 256) sA[e] = A[e];
    for (int e = tid; e < NS * NI; e += 256) sB[e] = B[e];
    __syncthreads();
    for (int e = tid; e < NS * NS; e += 256) Ka[0][e] = sA[e];
    for (int e = tid; e < NS * NI; e += 256) { Kb[0][e] = sB[e]; Kc[0][e] = 0.f; }
    __syncthreads();

    const float atab[5][5] = {
        {0.2f, 0.f, 0.f, 0.f, 0.f},
        {3.f / 40.f, 9.f / 40.f, 0.f, 0.f, 0.f},
        {44.f / 45.f, -56.f / 15.f, 32.f / 9.f, 0.f, 0.f},
        {19372.f / 6561.f, -25360.f / 2187.f, 64448.f / 6561.f, -212.f / 729.f, 0.f},
        {9017.f / 3168.f, -355.f / 33.f, 46732.f / 5247.f, 49.f / 176.f, -5103.f / 18656.f}};
    const float ctab[6] = {0.f, 0.2f, 0.3f, 0.8f, 8.f / 9.f, 1.f};

    for (int st = 1; st <= 5; ++st) {
        for (int e = tid; e < NS * NS; e += 256) {
            float acc = 0.f;
            for (int j = 0; j < st; ++j) acc += atab[st - 1][j] * Ka[j][e];
            Sa[e] = acc;
        }
        for (int e = tid; e < NS * NI; e += 256) {
            float ab = 0.f, ac = 0.f;
            for (int j = 0; j < st; ++j) {
                ab += atab[st - 1][j] * Kb[j][e];
                ac += atab[st - 1][j] * Kc[j][e];
            }
            Sb[e] = ab; Sc[e] = ac;
        }
        __syncthreads();
        {
            const int j = tid & 31, ig = tid >> 5;
            for (int r = 0; r < 4; ++r) {
                const int row = ig + 8 * r;
                float acc = 0.f;
                for (int k = 0; k < NS; ++k) acc += sA[row * NS + k] * Sa[k * NS + j];
                Ka[st][row * NS + j] = sA[row * NS + j] + dt * acc;
            }
            const int jb = tid & 7, rb = tid >> 3;
            float ab = 0.f, ac = 0.f;
            for (int k = 0; k < NS; ++k) {
                ab += sA[rb * NS + k] * Sb[k * NI + jb];
                ac += sA[rb * NS + k] * Sc[k * NI + jb];
            }
            Kb[st][rb * NI + jb] = sB[rb * NI + jb] + dt * ab;
            Kc[st][rb * NI + jb] = ctab[st] * sB[rb * NI + jb] + dt * ac;
        }
        __syncthreads();
    }

    const float btab[6] = {35.f / 384.f, 0.f, 500.f / 1113.f, 125.f / 192.f,
                           -2187.f / 6784.f, 11.f / 84.f};
    for (int e = tid; e < NS * NS; e += 256) {
        float acc = 0.f;
        for (int i2 = 0; i2 < 6; ++i2) acc += btab[i2] * Ka[i2][e];
        const float m = dt * acc + (((e / NS) == (e % NS)) ? 1.f : 0.f);
        ws[WS_M + e] = m;
        Pq[0][e] = m;
        Ms[e] = m;  // live copy of M for the F build
    }
    for (int e = tid; e < NS * NI; e += 256) {
        float ap = 0.f, aq = 0.f;
        for (int i2 = 0; i2 < 6; ++i2) {
            ap += btab[i2] * Kb[i2][e];
            aq += btab[i2] * Kc[i2][e];
        }
        const float P = dt * ap, Q = dt * aq;
        ws[WS_N0 + e] = P - Q;  // coefficient of u_n
        ws[WS_N1 + e] = Q;      // coefficient of u_{n+1}
        Sb[e] = P - Q;          // N0'
        Sc[e] = Q;              // N1'
    }
    __syncthreads();

    // ML = M^64 via 6 squarings; capture M^8 into Sa (dead after RK stages).
    int cur = 0;
    for (int itq = 0; itq < 6; ++itq) {
        const int j = tid & 31, ig = tid >> 5;
        for (int r = 0; r < 4; ++r) {
            const int row = ig + 8 * r;
            float acc = 0.f;
            for (int k = 0; k < NS; ++k) acc += Pq[cur][row * NS + k] * Pq[cur][k * NS + j];
            Pq[cur ^ 1][row * NS + j] = acc;
        }
        __syncthreads();
        cur ^= 1;
        if (itq == 2)
            for (int e = tid; e < NS * NS; e += 256) Sa[e] = Pq[cur][e];  // M^8
    }
    for (int e = tid; e < NS * NS; e += 256) ws[WS_ML + e] = Pq[cur][e];

    // ---- F build, log depth. chainbuf pages alias Ka (dead). ----
    float* cb = &Ka[0][0];  // 2 pages x 8 chains x 256 el = 4096 floats <= 6144
    const int rr = tid >> 3, mm = tid & 7;

    float mrow[NS], m8row[NS];
#pragma unroll
    for (int kk = 0; kk < NS; ++kk) { mrow[kk] = Ms[rr * NS + kk]; m8row[kk] = Sa[rr * NS + kk]; }

    // H = N0' + M N1'  -> F_63 (seed 0)
    {
        float acc = 0.f;
#pragma unroll
        for (int kk = 0; kk < NS; ++kk) acc += mrow[kk] * Sc[kk * NI + mm];
        const float h = Sb[tid] + acc;
        cb[tid] = h;
        ws[WS_F + 63 * (NS * NI) + tid] = h;
    }
    __syncthreads();
    // seeds S_i = M^8 S_{i-1} -> F_{63-8i}
    for (int i = 1; i < 8; ++i) {
        float acc = 0.f;
#pragma unroll
        for (int kk = 0; kk < NS; ++kk) acc += m8row[kk] * cb[(i - 1) * 256 + kk * NI + mm];
        cb[i * 256 + tid] = acc;
        ws[WS_F + (63 - 8 * i) * (NS * NI) + tid] = acc;
        __syncthreads();
    }
    // 7 parallel steps: advance all 8 chains by M
    int pp = 0;
    for (int k = 1; k < 8; ++k) {
        float acc[8];
#pragma unroll
        for (int i = 0; i < 8; ++i) {
            float a = 0.f;
#pragma unroll
            for (int kk = 0; kk < NS; ++kk) a += mrow[kk] * cb[pp * 2048 + i * 256 + kk * NI + mm];
            acc[i] = a;
        }
#pragma unroll
        for (int i = 0; i < 8; ++i) {
            cb[(pp ^ 1) * 2048 + i * 256 + tid] = acc[i];
            ws[WS_F + (63 - 8 * i - k) * (NS * NI) + tid] = acc[i];
        }
        __syncthreads();
        pp ^= 1;
    }
    ws[WS_F + 64 * (NS * NI) + tid] = Sc[tid];  // F_64 = N1'
}

// ---------------------------------------------------------------------------
// Phase 1 (GEMM form, v3b): v[b][c] = sum_{j=0..64} F_j u_{t0+j}
// F[0..63] staged in 64 KB LDS transposed to sF[j][q][s8] (reads conflict-free);
// staging writes linear in LDS, permutation on the L2-resident global read.
// ---------------------------------------------------------------------------
__global__ __launch_bounds__(256, 2) void k_phase1(const float* __restrict__ u,
                                                   float* __restrict__ ws) {
    __shared__ float4 sF[64 * 64];  // [j][q][s8], 65536 B

    const int tid = threadIdx.x;

    // linear LDS write; permuted global read: sF[j*64 + q*8 + s] = Fg[j*64 + s*8 + q]
    const float4* Fg = (const float4*)(ws + WS_F);
    for (int idx = tid; idx < 64 * 64; idx += 256) {
        const int j = idx >> 6, q = (idx >> 3) & 7, s = idx & 7;
        sF[idx] = Fg[(j << 6) + (s << 3) + q];
    }
    __syncthreads();

    const int task = blockIdx.x * 4 + (tid >> 6);
    const int c = task % (NCHUNKS - 1), g = task / (NCHUNKS - 1);
    const int l = tid & 63;
    const int beta = l >> 3, s8 = l & 7;
    const int b = g * 8 + beta;
    const int t0 = c * LCH;
    const float* ub = u + ((size_t)b * TT + t0) * NI;

    float4 ua = ld4(ub), uc = ld4(ub + 4);
    float a0 = 0.f, a1 = 0.f, a2 = 0.f, a3 = 0.f;

#pragma unroll 4
    for (int j = 0; j < 64; ++j) {
        // prefetch next u (always valid: t0+64 <= 4032)
        const float4 na = ld4(ub + (j + 1) * NI);
        const float4 nb = ld4(ub + (j + 1) * NI + 4);
        const float4* fj = &sF[(j << 6) + s8];
        const float4 f0 = fj[0], f1 = fj[8], f2 = fj[16], f3 = fj[24];
        const float4 f4 = fj[32], f5 = fj[40], f6 = fj[48], f7 = fj[56];
        a0 += dot4(f0, ua) + dot4(f1, uc);
        a1 += dot4(f2, ua) + dot4(f3, uc);
        a2 += dot4(f4, ua) + dot4(f5, uc);
        a3 += dot4(f6, ua) + dot4(f7, uc);
        ua = na; uc = nb;
    }

    // j = 64 tail: F_64 rows from global (tiny, L2-resident)
    const float* Ft = ws + WS_F + 64 * (NS * NI) + 32 * s8;
    a0 += dot4(ld4(Ft), ua) + dot4(ld4(Ft + 4), uc);
    a1 += dot4(ld4(Ft + 8), ua) + dot4(ld4(Ft + 12), uc);
    a2 += dot4(ld4(Ft + 16), ua) + dot4(ld4(Ft + 20), uc);
    a3 += dot4(ld4(Ft + 24), ua) + dot4(ld4(Ft + 28), uc);

    *(float4*)(ws + WS_V + ((size_t)b * NCHUNKS + c) * NS + 4 * s8) =
        make_float4(a0, a1, a2, a3);
}

// ---------------------------------------------------------------------------
// Phase 2: propagate chunk start states. One wave per batch.
// ---------------------------------------------------------------------------
__global__ __launch_bounds__(64) void k_phase2(const float* __restrict__ x0,
                                               float* __restrict__ ws) {
    const float* ML = ws + WS_ML;
    const float* v = ws + WS_V;
    float* sst = ws + WS_S;
    const int b = blockIdx.x;
    const int l = threadIdx.x, i = l & 31, h = l >> 5;

    float mlr[16];
#pragma unroll
    for (int jj = 0; jj < 16; ++jj) mlr[jj] = ML[i * NS + 16 * h + jj];

    float x = x0[b * NS + i];
    for (int c = 0; c < NCHUNKS; ++c) {
        if (h == 0) sst[((size_t)b * NCHUNKS + c) * NS + i] = x;
        if (c == NCHUNKS - 1) break;
        float p = 0.f;
#pragma unroll
        for (int jj = 0; jj < 16; ++jj) p += mlr[jj] * __shfl(x, 16 * h + jj, 64);
        p += __shfl_xor(p, 32, 64);
        x = p + v[((size_t)b * NCHUNKS + c) * NS + i];
    }
}

// ---------------------------------------------------------------------------
// Phase 3 (v4): replay chunks, writing xs and ys (fused).
// Changes vs the 111-us round-4/6 version (same ownership: 8 batches/wave,
// 8 lanes/batch, 4 rows/lane, 172 VGPR, 2 waves/SIMD):
//  - x exchange via __shfl (ds_bpermute) instead of LDS: removes the
//    ds_write -> lgkmcnt(0) -> 8x ds_read_b128 round-trip (~250+ cy of pure
//    latency per step) and all barriers from the serial chain.
//  - pointer-bumped xs/y/u addresses (no per-step 64-bit mads).
//  - split accumulation chains (even/odd M partials, two y halves) to cut
//    the dependent-FMA chain ~3x.
// DO NOT cap VGPRs below demand: (64,3) forced 84 VGPR -> spill -> 2.9 GB
// scratch fetch, 1099 us (round 5).
// ---------------------------------------------------------------------------
__global__ __launch_bounds__(64, 1) void k_phase3(const float* __restrict__ u,
                                                  float* __restrict__ ws,
                                                  float* __restrict__ out,
                                                  const float* __restrict__ Cc,
                                                  const float* __restrict__ Dd) {
    const float* M = ws + WS_M;
    const float* N0 = ws + WS_N0;
    const float* N1 = ws + WS_N1;

    const int task = blockIdx.x;
    const int c = task % NCHUNKS, g = task / NCHUNKS;
    const int l = threadIdx.x;
    const int beta = l >> 3, s8 = l & 7;
    const int b = g * 8 + beta;
    const int src_base = l & 56;  // beta * 8: lane owning xq[jj] is src_base + jj

    // cache M rows 4*s8 .. 4*s8+3 (128 VGPRs)
    float4 mq[4][8];
#pragma unroll
    for (int r = 0; r < 4; ++r)
#pragma unroll
        for (int jj = 0; jj < 8; ++jj) mq[r][jj] = ld4(M + (4 * s8 + r) * NS + 4 * jj);

    float4 n0q[4][2], n1q[4][2];
#pragma unroll
    for (int r = 0; r < 4; ++r) {
        n0q[r][0] = ld4(N0 + (4 * s8 + r) * NI);
        n0q[r][1] = ld4(N0 + (4 * s8 + r) * NI + 4);
        n1q[r][0] = ld4(N1 + (4 * s8 + r) * NI);
        n1q[r][1] = ld4(N1 + (4 * s8 + r) * NI + 4);
    }

    float4 cq[8], dq[2];
#pragma unroll
    for (int jj = 0; jj < 8; ++jj) cq[jj] = ld4(Cc + s8 * NS + 4 * jj);
    dq[0] = ld4(Dd + s8 * NI);
    dq[1] = ld4(Dd + s8 * NI + 4);

    const int t0 = c * LCH;
    const float* ub = u + (size_t)b * TT * NI;
    const float* u_last = ub + (size_t)(TT - 1) * NI;
    const float* up = ub + (size_t)t0 * NI;
    float4 u0a = ld4(up), u0b = ld4(up + 4);
    float4 u1a = ld4(up + NI), u1b = ld4(up + NI + 4);
    const float* up2 = up + 2 * NI;  // u[t+2] candidate, bumped each step

    float4 mine = ld4(ws + WS_S + ((size_t)b * NCHUNKS + c) * NS + 4 * s8);

    float* xp = out + ((size_t)b * TT + t0) * NS + 4 * s8;
    float* yp = out + (size_t)BATCH * TT * NS + ((size_t)b * TT + t0) * NO + s8;

    for (int js = 0; js < LCH; ++js) {
        // register x-exchange: xq[jj] = mine of lane src_base+jj (no LDS, no barrier)
        float4 xq[8];
#pragma unroll
        for (int jj = 0; jj < 8; ++jj) {
            xq[jj].x = __shfl(mine.x, src_base + jj, 64);
            xq[jj].y = __shfl(mine.y, src_base + jj, 64);
            xq[jj].z = __shfl(mine.z, src_base + jj, 64);
            xq[jj].w = __shfl(mine.w, src_base + jj, 64);
        }

        // prefetch u[t+2] (pointer-clamped to last sample; dead values unused)
        const float* uq = (up2 > u_last) ? u_last : up2;
        const float4 u2a = ld4(uq);
        const float4 u2b = ld4(uq + 4);

        // store xs[b][t][4*s8 .. 4*s8+3]
        *(float4*)xp = mine;

        // y[b][t][s8] = C x + D u, two-way split accumulation
        float ya = dot4(cq[0], xq[0]) + dot4(cq[1], xq[1]) + dot4(cq[2], xq[2]) + dot4(cq[3], xq[3]);
        float yb = dot4(cq[4], xq[4]) + dot4(cq[5], xq[5]) + dot4(cq[6], xq[6]) + dot4(cq[7], xq[7]);
        ya += dot4(dq[0], u0a);
        yb += dot4(dq[1], u0b);
        *yp = ya + yb;

        if (js < LCH - 1) {
            float w0, w1, w2, w3;
#pragma unroll
            for (int r = 0; r < 4; ++r) {
                const float pn = dot4(n0q[r][0], u0a) + dot4(n0q[r][1], u0b) +
                                 dot4(n1q[r][0], u1a) + dot4(n1q[r][1], u1b);
                const float pe = dot4(mq[r][0], xq[0]) + dot4(mq[r][2], xq[2]) +
                                 dot4(mq[r][4], xq[4]) + dot4(mq[r][6], xq[6]);
                const float po = dot4(mq[r][1], xq[1]) + dot4(mq[r][3], xq[3]) +
                                 dot4(mq[r][5], xq[5]) + dot4(mq[r][7], xq[7]);
                const float w = pn + pe + po;
                if (r == 0) w0 = w; else if (r == 1) w1 = w; else if (r == 2) w2 = w; else w3 = w;
            }
            mine = make_float4(w0, w1, w2, w3);
            u0a = u1a; u0b = u1b;
            u1a = u2a; u1b = u2b;
        }
        xp += NS;
        yp += NO;
        up2 += NI;
    }
}

extern "C" void kernel_launch(void* const* d_in, const int* in_sizes, int n_in,
                              void* d_out, int out_size, void* d_ws, size_t ws_size,
                              hipStream_t stream) {
    const float* t = (const float*)d_in[0];
    const float* u = (const float*)d_in[1];
    const float* x0 = (const float*)d_in[2];
    const float* A = (const float*)d_in[3];
    const float* B = (const float*)d_in[4];
    const float* C = (const float*)d_in[5];
    const float* D = (const float*)d_in[6];
    float* out = (float*)d_out;
    float* ws = (float*)d_ws;

    k_pre<<<dim3(1), dim3(256), 0, stream>>>(t, A, B, ws);
    k_phase1<<<dim3(8 * (NCHUNKS - 1)), dim3(256), 0, stream>>>(u, ws);
    k_phase2<<<dim3(BATCH), dim3(64), 0, stream>>>(x0, ws);
    k_phase3<<<dim3(32 * NCHUNKS), dim3(64), 0, stream>>>(u, ws, out, C, D);
}

// Round 8
// 361.711 us; speedup vs baseline: 1.0523x; 1.0523x over previous
//
#include <hip/hip_runtime.h>

#define BATCH 256
#define TT 4096
#define NS 32
#define NI 8
#define NO 8
#define LCH 64
#define NCHUNKS 64  // TT / LCH

// ws layout (floats)
#define WS_M  0
#define WS_N0 1024
#define WS_N1 1280
#define WS_ML 1536
#define WS_V  2560
#define WS_S  (2560 + BATCH * NCHUNKS * NS)
#define WS_F  (WS_S + BATCH * NCHUNKS * NS)  // [LCH+1][NS][NI]

__device__ __forceinline__ float dot4(float4 a, float4 b) {
    return a.x * b.x + a.y * b.y + a.z * b.z + a.w * b.w;
}
__device__ __forceinline__ float4 ld4(const float* p) { return *(const float4*)p; }
__device__ __forceinline__ float2 ld2(const float* p) { return *(const float2*)p; }

// ---------------------------------------------------------------------------
// Kernel 0: build step matrices M, N0, N1 (one Dopri5 step == x' = M x + N0 u0 + N1 u1),
// ML = M^64, and convolution kernels F_j (v[b][c] = sum_j F_j u_{t0+j}).
// F build is log-depth: F_j = M^(63-j) H with H = N0' + M N1'; M^8 captured
// during the ML squarings; 7 serial seed steps + 7 parallel 8-chain steps.
// ---------------------------------------------------------------------------
__global__ __launch_bounds__(256) void k_pre(const float* __restrict__ tarr,
                                             const float* __restrict__ A,
                                             const float* __restrict__ B,
                                             float* __restrict__ ws) {
    __shared__ float sA[NS * NS], sB[NS * NI];
    __shared__ float Ka[6][NS * NS];
    __shared__ float Kb[6][NS * NI];
    __shared__ float Kc[6][NS * NI];
    __shared__ float Sa[NS * NS], Sb[NS * NI], Sc[NS * NI];
    __shared__ float Pq[2][NS * NS];
    __shared__ float Ms[NS * NS];

    const int tid = threadIdx.x;
    const float dt = tarr[1] - tarr[0];

    for (int e = tid; e < NS * NS; e += 256) sA[e] = A[e];
    for (int e = tid; e < NS * NI; e += 256) sB[e] = B[e];
    __syncthreads();
    for (int e = tid; e < NS * NS; e += 256) Ka[0][e] = sA[e];
    for (int e = tid; e < NS * NI; e += 256) { Kb[0][e] = sB[e]; Kc[0][e] = 0.f; }
    __syncthreads();

    const float atab[5][5] = {
        {0.2f, 0.f, 0.f, 0.f, 0.f},
        {3.f / 40.f, 9.f / 40.f, 0.f, 0.f, 0.f},
        {44.f / 45.f, -56.f / 15.f, 32.f / 9.f, 0.f, 0.f},
        {19372.f / 6561.f, -25360.f / 2187.f, 64448.f / 6561.f, -212.f / 729.f, 0.f},
        {9017.f / 3168.f, -355.f / 33.f, 46732.f / 5247.f, 49.f / 176.f, -5103.f / 18656.f}};
    const float ctab[6] = {0.f, 0.2f, 0.3f, 0.8f, 8.f / 9.f, 1.f};

    for (int st = 1; st <= 5; ++st) {
        for (int e = tid; e < NS * NS; e += 256) {
            float acc = 0.f;
            for (int j = 0; j < st; ++j) acc += atab[st - 1][j] * Ka[j][e];
            Sa[e] = acc;
        }
        for (int e = tid; e < NS * NI; e += 256) {
            float ab = 0.f, ac = 0.f;
            for (int j = 0; j < st; ++j) {
                ab += atab[st - 1][j] * Kb[j][e];
                ac += atab[st - 1][j] * Kc[j][e];
            }
            Sb[e] = ab; Sc[e] = ac;
        }
        __syncthreads();
        {
            const int j = tid & 31, ig = tid >> 5;
            for (int r = 0; r < 4; ++r) {
                const int row = ig + 8 * r;
                float acc = 0.f;
                for (int k = 0; k < NS; ++k) acc += sA[row * NS + k] * Sa[k * NS + j];
                Ka[st][row * NS + j] = sA[row * NS + j] + dt * acc;
            }
            const int jb = tid & 7, rb = tid >> 3;
            float ab = 0.f, ac = 0.f;
            for (int k = 0; k < NS; ++k) {
                ab += sA[rb * NS + k] * Sb[k * NI + jb];
                ac += sA[rb * NS + k] * Sc[k * NI + jb];
            }
            Kb[st][rb * NI + jb] = sB[rb * NI + jb] + dt * ab;
            Kc[st][rb * NI + jb] = ctab[st] * sB[rb * NI + jb] + dt * ac;
        }
        __syncthreads();
    }

    const float btab[6] = {35.f / 384.f, 0.f, 500.f / 1113.f, 125.f / 192.f,
                           -2187.f / 6784.f, 11.f / 84.f};
    for (int e = tid; e < NS * NS; e += 256) {
        float acc = 0.f;
        for (int i2 = 0; i2 < 6; ++i2) acc += btab[i2] * Ka[i2][e];
        const float m = dt * acc + (((e / NS) == (e % NS)) ? 1.f : 0.f);
        ws[WS_M + e] = m;
        Pq[0][e] = m;
        Ms[e] = m;  // live copy of M for the F build
    }
    for (int e = tid; e < NS * NI; e += 256) {
        float ap = 0.f, aq = 0.f;
        for (int i2 = 0; i2 < 6; ++i2) {
            ap += btab[i2] * Kb[i2][e];
            aq += btab[i2] * Kc[i2][e];
        }
        const float P = dt * ap, Q = dt * aq;
        ws[WS_N0 + e] = P - Q;  // coefficient of u_n
        ws[WS_N1 + e] = Q;      // coefficient of u_{n+1}
        Sb[e] = P - Q;          // N0'
        Sc[e] = Q;              // N1'
    }
    __syncthreads();

    // ML = M^64 via 6 squarings; capture M^8 into Sa (dead after RK stages).
    int cur = 0;
    for (int itq = 0; itq < 6; ++itq) {
        const int j = tid & 31, ig = tid >> 5;
        for (int r = 0; r < 4; ++r) {
            const int row = ig + 8 * r;
            float acc = 0.f;
            for (int k = 0; k < NS; ++k) acc += Pq[cur][row * NS + k] * Pq[cur][k * NS + j];
            Pq[cur ^ 1][row * NS + j] = acc;
        }
        __syncthreads();
        cur ^= 1;
        if (itq == 2)
            for (int e = tid; e < NS * NS; e += 256) Sa[e] = Pq[cur][e];  // M^8
    }
    for (int e = tid; e < NS * NS; e += 256) ws[WS_ML + e] = Pq[cur][e];

    // ---- F build, log depth. chainbuf pages alias Ka (dead). ----
    float* cb = &Ka[0][0];  // 2 pages x 8 chains x 256 el = 4096 floats <= 6144
    const int rr = tid >> 3, mm = tid & 7;

    float mrow[NS], m8row[NS];
#pragma unroll
    for (int kk = 0; kk < NS; ++kk) { mrow[kk] = Ms[rr * NS + kk]; m8row[kk] = Sa[rr * NS + kk]; }

    // H = N0' + M N1'  -> F_63 (seed 0)
    {
        float acc = 0.f;
#pragma unroll
        for (int kk = 0; kk < NS; ++kk) acc += mrow[kk] * Sc[kk * NI + mm];
        const float h = Sb[tid] + acc;
        cb[tid] = h;
        ws[WS_F + 63 * (NS * NI) + tid] = h;
    }
    __syncthreads();
    // seeds S_i = M^8 S_{i-1} -> F_{63-8i}
    for (int i = 1; i < 8; ++i) {
        float acc = 0.f;
#pragma unroll
        for (int kk = 0; kk < NS; ++kk) acc += m8row[kk] * cb[(i - 1) * 256 + kk * NI + mm];
        cb[i * 256 + tid] = acc;
        ws[WS_F + (63 - 8 * i) * (NS * NI) + tid] = acc;
        __syncthreads();
    }
    // 7 parallel steps: advance all 8 chains by M
    int pp = 0;
    for (int k = 1; k < 8; ++k) {
        float acc[8];
#pragma unroll
        for (int i = 0; i < 8; ++i) {
            float a = 0.f;
#pragma unroll
            for (int kk = 0; kk < NS; ++kk) a += mrow[kk] * cb[pp * 2048 + i * 256 + kk * NI + mm];
            acc[i] = a;
        }
#pragma unroll
        for (int i = 0; i < 8; ++i) {
            cb[(pp ^ 1) * 2048 + i * 256 + tid] = acc[i];
            ws[WS_F + (63 - 8 * i - k) * (NS * NI) + tid] = acc[i];
        }
        __syncthreads();
        pp ^= 1;
    }
    ws[WS_F + 64 * (NS * NI) + tid] = Sc[tid];  // F_64 = N1'
}

// ---------------------------------------------------------------------------
// Phase 1 (GEMM form, v3b): v[b][c] = sum_{j=0..64} F_j u_{t0+j}
// F[0..63] staged in 64 KB LDS transposed to sF[j][q][s8] (reads conflict-free);
// staging writes linear in LDS, permutation on the L2-resident global read.
// ---------------------------------------------------------------------------
__global__ __launch_bounds__(256, 2) void k_phase1(const float* __restrict__ u,
                                                   float* __restrict__ ws) {
    __shared__ float4 sF[64 * 64];  // [j][q][s8], 65536 B

    const int tid = threadIdx.x;

    // linear LDS write; permuted global read: sF[j*64 + q*8 + s] = Fg[j*64 + s*8 + q]
    const float4* Fg = (const float4*)(ws + WS_F);
    for (int idx = tid; idx < 64 * 64; idx += 256) {
        const int j = idx >> 6, q = (idx >> 3) & 7, s = idx & 7;
        sF[idx] = Fg[(j << 6) + (s << 3) + q];
    }
    __syncthreads();

    const int task = blockIdx.x * 4 + (tid >> 6);
    const int c = task % (NCHUNKS - 1), g = task / (NCHUNKS - 1);
    const int l = tid & 63;
    const int beta = l >> 3, s8 = l & 7;
    const int b = g * 8 + beta;
    const int t0 = c * LCH;
    const float* ub = u + ((size_t)b * TT + t0) * NI;

    float4 ua = ld4(ub), uc = ld4(ub + 4);
    float a0 = 0.f, a1 = 0.f, a2 = 0.f, a3 = 0.f;

#pragma unroll 4
    for (int j = 0; j < 64; ++j) {
        // prefetch next u (always valid: t0+64 <= 4032)
        const float4 na = ld4(ub + (j + 1) * NI);
        const float4 nb = ld4(ub + (j + 1) * NI + 4);
        const float4* fj = &sF[(j << 6) + s8];
        const float4 f0 = fj[0], f1 = fj[8], f2 = fj[16], f3 = fj[24];
        const float4 f4 = fj[32], f5 = fj[40], f6 = fj[48], f7 = fj[56];
        a0 += dot4(f0, ua) + dot4(f1, uc);
        a1 += dot4(f2, ua) + dot4(f3, uc);
        a2 += dot4(f4, ua) + dot4(f5, uc);
        a3 += dot4(f6, ua) + dot4(f7, uc);
        ua = na; uc = nb;
    }

    // j = 64 tail: F_64 rows from global (tiny, L2-resident)
    const float* Ft = ws + WS_F + 64 * (NS * NI) + 32 * s8;
    a0 += dot4(ld4(Ft), ua) + dot4(ld4(Ft + 4), uc);
    a1 += dot4(ld4(Ft + 8), ua) + dot4(ld4(Ft + 12), uc);
    a2 += dot4(ld4(Ft + 16), ua) + dot4(ld4(Ft + 20), uc);
    a3 += dot4(ld4(Ft + 24), ua) + dot4(ld4(Ft + 28), uc);

    *(float4*)(ws + WS_V + ((size_t)b * NCHUNKS + c) * NS + 4 * s8) =
        make_float4(a0, a1, a2, a3);
}

// ---------------------------------------------------------------------------
// Phase 2: propagate chunk start states. One wave per batch.
// ---------------------------------------------------------------------------
__global__ __launch_bounds__(64) void k_phase2(const float* __restrict__ x0,
                                               float* __restrict__ ws) {
    const float* ML = ws + WS_ML;
    const float* v = ws + WS_V;
    float* sst = ws + WS_S;
    const int b = blockIdx.x;
    const int l = threadIdx.x, i = l & 31, h = l >> 5;

    float mlr[16];
#pragma unroll
    for (int jj = 0; jj < 16; ++jj) mlr[jj] = ML[i * NS + 16 * h + jj];

    float x = x0[b * NS + i];
    for (int c = 0; c < NCHUNKS; ++c) {
        if (h == 0) sst[((size_t)b * NCHUNKS + c) * NS + i] = x;
        if (c == NCHUNKS - 1) break;
        float p = 0.f;
#pragma unroll
        for (int jj = 0; jj < 16; ++jj) p += mlr[jj] * __shfl(x, 16 * h + jj, 64);
        p += __shfl_xor(p, 32, 64);
        x = p + v[((size_t)b * NCHUNKS + c) * NS + i];
    }
}

// ---------------------------------------------------------------------------
// Phase 3 (v5): replay chunks, writing xs and ys (fused).
// Occupancy attack at constant algorithm: 2 batches/wave, 32 lanes/batch.
// Lane (beta2=l>>5, h=(l>>3)&3, s8=l&7) owns rows 4*s8..4*s8+3 but only
// column quarter 8h..8h+7 of M (mq: 32 VGPR vs 128 before). Partial row-dots
// (M + N + y, N/C/D/u split by h too) are reduced across the 4 h-lanes with
// shfl_xor(8,16) - 10 small shuffles, the RIGHT use of shfl (round-7 lesson:
// bulk 16B/lane exchange via LDS b128, never 32 bpermutes).
// x-exchange stays LDS b128 (2 reads/lane, broadcast within 8-lane groups).
// Per-lane demand ~105 VGPR -> __launch_bounds__(64,4) caps at 128 with real
// headroom (NOT a forced under-allocation; round-5 spill was demand>>cap).
// ---------------------------------------------------------------------------
__global__ __launch_bounds__(64, 4) void k_phase3(const float* __restrict__ u,
                                                  float* __restrict__ ws,
                                                  float* __restrict__ out,
                                                  const float* __restrict__ Cc,
                                                  const float* __restrict__ Dd) {
    const float* M = ws + WS_M;
    const float* N0 = ws + WS_N0;
    const float* N1 = ws + WS_N1;

    const int task = blockIdx.x;
    const int c = task % NCHUNKS, g = task / NCHUNKS;
    const int l = threadIdx.x;
    const int beta2 = l >> 5;          // batch within wave (2)
    const int h = (l >> 3) & 3;        // column quarter
    const int s8 = l & 7;              // 4-row group
    const int b = g * 2 + beta2;

    // M rows 4*s8..4*s8+3, columns 8h..8h+7 (32 VGPR)
    float4 mq[4][2];
#pragma unroll
    for (int r = 0; r < 4; ++r) {
        mq[r][0] = ld4(M + (4 * s8 + r) * NS + 8 * h);
        mq[r][1] = ld4(M + (4 * s8 + r) * NS + 8 * h + 4);
    }
    // N0/N1 rows 4*s8..4*s8+3, u-columns 2h..2h+1
    float2 n0q[4], n1q[4];
#pragma unroll
    for (int r = 0; r < 4; ++r) {
        n0q[r] = ld2(N0 + (4 * s8 + r) * NI + 2 * h);
        n1q[r] = ld2(N1 + (4 * s8 + r) * NI + 2 * h);
    }
    // C row s8 (output o=s8), columns 8h..8h+7; D row s8, columns 2h..2h+1
    float4 cq[2];
    cq[0] = ld4(Cc + s8 * NS + 8 * h);
    cq[1] = ld4(Cc + s8 * NS + 8 * h + 4);
    const float2 dq = ld2(Dd + s8 * NI + 2 * h);

    const int t0 = c * LCH;
    const float* ub = u + (size_t)b * TT * NI;
    const float* upl = ub + (size_t)t0 * NI + 2 * h;        // lane's u slice
    const float* u_lastl = ub + (size_t)(TT - 1) * NI + 2 * h;
    float2 u0h = ld2(upl);
    float2 u1h = ld2(upl + NI);
    const float* upl2 = upl + 2 * NI;                        // u[t+2] candidate

    float4 mine = ld4(ws + WS_S + ((size_t)b * NCHUNKS + c) * NS + 4 * s8);

    float* xp = out + ((size_t)b * TT + t0) * NS + 4 * s8;
    float* yp = out + (size_t)BATCH * TT * NS + ((size_t)b * TT + t0) * NO + s8;

    // x buffer: [dbuf][batch][s8] float4, 256 B. Writers: h==0 lanes.
    __shared__ float4 xb[2][2 * 8];

    if (h == 0) xb[0][beta2 * 8 + s8] = mine;
    asm volatile("s_waitcnt lgkmcnt(0)" ::: "memory");
    __builtin_amdgcn_sched_barrier(0);

    int cur = 0;
    for (int js = 0; js < LCH; ++js) {
        // x slice rows 8h..8h+7 (slots 2h, 2h+1) - broadcast reads, no conflict
        float4 xq0 = xb[cur][beta2 * 8 + 2 * h];
        float4 xq1 = xb[cur][beta2 * 8 + 2 * h + 1];

        // prefetch u[t+2] (pointer-clamped; dead values never consumed)
        const float* uq = (upl2 > u_lastl) ? u_lastl : upl2;
        const float2 u2h = ld2(uq);

        // y partial (quarter): C x + D u over cols 8h..8h+7 / 2h..2h+1
        float yv = dot4(cq[0], xq0) + dot4(cq[1], xq1) + dq.x * u0h.x + dq.y * u0h.y;

        if (js < LCH - 1) {
            // next-state partials: M quarter + N quarter
            float w0, w1, w2, w3;
#pragma unroll
            for (int r = 0; r < 4; ++r) {
                float wv = dot4(mq[r][0], xq0) + dot4(mq[r][1], xq1);
                wv += n0q[r].x * u0h.x + n0q[r].y * u0h.y +
                      n1q[r].x * u1h.x + n1q[r].y * u1h.y;
                if (r == 0) w0 = wv; else if (r == 1) w1 = wv; else if (r == 2) w2 = wv; else w3 = wv;
            }
            // reduce the 5 partials across the 4 h-lanes (xor 8, xor 16)
            yv += __shfl_xor(yv, 8, 64);
            w0 += __shfl_xor(w0, 8, 64);
            w1 += __shfl_xor(w1, 8, 64);
            w2 += __shfl_xor(w2, 8, 64);
            w3 += __shfl_xor(w3, 8, 64);
            yv += __shfl_xor(yv, 16, 64);
            w0 += __shfl_xor(w0, 16, 64);
            w1 += __shfl_xor(w1, 16, 64);
            w2 += __shfl_xor(w2, 16, 64);
            w3 += __shfl_xor(w3, 16, 64);

            if (h == 0) {
                *(float4*)xp = mine;  // xs[b][t][4s8..4s8+3]
                *yp = yv;             // y[b][t][s8]
            }
            mine = make_float4(w0, w1, w2, w3);
            if (h == 0) xb[cur ^ 1][beta2 * 8 + s8] = mine;
            u0h = u1h;
            u1h = u2h;
        } else {
            yv += __shfl_xor(yv, 8, 64);
            yv += __shfl_xor(yv, 16, 64);
            if (h == 0) {
                *(float4*)xp = mine;
                *yp = yv;
            }
        }
        asm volatile("s_waitcnt lgkmcnt(0)" ::: "memory");
        __builtin_amdgcn_sched_barrier(0);
        cur ^= 1;
        xp += NS;
        yp += NO;
        upl2 += NI;
    }
}

extern "C" void kernel_launch(void* const* d_in, const int* in_sizes, int n_in,
                              void* d_out, int out_size, void* d_ws, size_t ws_size,
                              hipStream_t stream) {
    const float* t = (const float*)d_in[0];
    const float* u = (const float*)d_in[1];
    const float* x0 = (const float*)d_in[2];
    const float* A = (const float*)d_in[3];
    const float* B = (const float*)d_in[4];
    const float* C = (const float*)d_in[5];
    const float* D = (const float*)d_in[6];
    float* out = (float*)d_out;
    float* ws = (float*)d_ws;

    k_pre<<<dim3(1), dim3(256), 0, stream>>>(t, A, B, ws);
    k_phase1<<<dim3(8 * (NCHUNKS - 1)), dim3(256), 0, stream>>>(u, ws);
    k_phase2<<<dim3(BATCH), dim3(64), 0, stream>>>(x0, ws);
    k_phase3<<<dim3(128 * NCHUNKS), dim3(64), 0, stream>>>(u, ws, out, C, D);
}

// Round 9
// 352.090 us; speedup vs baseline: 1.0811x; 1.0273x over previous
//
#include <hip/hip_runtime.h>

#define BATCH 256
#define TT 4096
#define NS 32
#define NI 8
#define NO 8
#define LCH 64
#define NCHUNKS 64  // TT / LCH

// ws layout (floats)
#define WS_M  0
#define WS_N0 1024
#define WS_N1 1280
#define WS_ML 1536
#define WS_V  2560
#define WS_S  (2560 + BATCH * NCHUNKS * NS)
#define WS_F  (WS_S + BATCH * NCHUNKS * NS)   // [LCH+1][NS][NI], PAIR-PACKED (fidx)
#define WS_MP (WS_F + 65 * NS * NI)           // M pair-packed: [s8][rp][col*2+par]

__device__ __forceinline__ float dot4(float4 a, float4 b) {
    return a.x * b.x + a.y * b.y + a.z * b.z + a.w * b.w;
}
__device__ __forceinline__ float4 ld4(const float* p) { return *(const float4*)p; }

// packed-pair FMA helpers: two independent fmaf into a float2 -> v_pk_fma_f32
__device__ __forceinline__ void fma2(float2& acc, float2 a, float s) {
    acc.x = fmaf(a.x, s, acc.x);
    acc.y = fmaf(a.y, s, acc.y);
}
__device__ __forceinline__ void fma22(float2& acc, float2 a, float2 b) {
    acc.x = fmaf(a.x, b.x, acc.x);
    acc.y = fmaf(a.y, b.y, acc.y);
}

// F element (row rr, col mm) -> packed float offset within a 256-float F_j block.
// Pairs adjacent rows (rr&1) in .x/.y; XOR-swizzles the float4 slot by s8 so
// phase1's 8 s8-groups read 8 distinct bank groups (conflict-free).
__device__ __forceinline__ int fidx(int rr, int mm) {
    const int s8 = rr >> 2, rp = (rr >> 1) & 1, par = rr & 1;
    const int q = rp * 16 + mm * 2 + par;           // 0..31 within s8 region
    return s8 * 32 + (((q >> 2) ^ s8) << 2) + (q & 3);
}

// ---------------------------------------------------------------------------
// Kernel 0: build step matrices M, N0, N1, ML = M^64, and convolution kernels
// F_j (v[b][c] = sum_j F_j u_{t0+j}).  F and M are additionally written in
// pair-packed layouts (WS_F packed via fidx, WS_MP) for the pk-FMA consumers.
// F build is log-depth: F_j = M^(63-j) H, H = N0' + M N1'; M^8 captured
// during the ML squarings; 7 serial seed steps + 7 parallel 8-chain steps.
// ---------------------------------------------------------------------------
__global__ __launch_bounds__(256) void k_pre(const float* __restrict__ tarr,
                                             const float* __restrict__ A,
                                             const float* __restrict__ B,
                                             float* __restrict__ ws) {
    __shared__ float sA[NS * NS], sB[NS * NI];
    __shared__ float Ka[6][NS * NS];
    __shared__ float Kb[6][NS * NI];
    __shared__ float Kc[6][NS * NI];
    __shared__ float Sa[NS * NS], Sb[NS * NI], Sc[NS * NI];
    __shared__ float Pq[2][NS * NS];
    __shared__ float Ms[NS * NS];

    const int tid = threadIdx.x;
    const float dt = tarr[1] - tarr[0];

    for (int e = tid; e < NS * NS; e += 256) sA[e] = A[e];
    for (int e = tid; e < NS * NI; e += 256) sB[e] = B[e];
    __syncthreads();
    for (int e = tid; e < NS * NS; e += 256) Ka[0][e] = sA[e];
    for (int e = tid; e < NS * NI; e += 256) { Kb[0][e] = sB[e]; Kc[0][e] = 0.f; }
    __syncthreads();

    const float atab[5][5] = {
        {0.2f, 0.f, 0.f, 0.f, 0.f},
        {3.f / 40.f, 9.f / 40.f, 0.f, 0.f, 0.f},
        {44.f / 45.f, -56.f / 15.f, 32.f / 9.f, 0.f, 0.f},
        {19372.f / 6561.f, -25360.f / 2187.f, 64448.f / 6561.f, -212.f / 729.f, 0.f},
        {9017.f / 3168.f, -355.f / 33.f, 46732.f / 5247.f, 49.f / 176.f, -5103.f / 18656.f}};
    const float ctab[6] = {0.f, 0.2f, 0.3f, 0.8f, 8.f / 9.f, 1.f};

    for (int st = 1; st <= 5; ++st) {
        for (int e = tid; e < NS * NS; e += 256) {
            float acc = 0.f;
            for (int j = 0; j < st; ++j) acc += atab[st - 1][j] * Ka[j][e];
            Sa[e] = acc;
        }
        for (int e = tid; e < NS * NI; e += 256) {
            float ab = 0.f, ac = 0.f;
            for (int j = 0; j < st; ++j) {
                ab += atab[st - 1][j] * Kb[j][e];
                ac += atab[st - 1][j] * Kc[j][e];
            }
            Sb[e] = ab; Sc[e] = ac;
        }
        __syncthreads();
        {
            const int j = tid & 31, ig = tid >> 5;
            for (int r = 0; r < 4; ++r) {
                const int row = ig + 8 * r;
                float acc = 0.f;
                for (int k = 0; k < NS; ++k) acc += sA[row * NS + k] * Sa[k * NS + j];
                Ka[st][row * NS + j] = sA[row * NS + j] + dt * acc;
            }
            const int jb = tid & 7, rb = tid >> 3;
            float ab = 0.f, ac = 0.f;
            for (int k = 0; k < NS; ++k) {
                ab += sA[rb * NS + k] * Sb[k * NI + jb];
                ac += sA[rb * NS + k] * Sc[k * NI + jb];
            }
            Kb[st][rb * NI + jb] = sB[rb * NI + jb] + dt * ab;
            Kc[st][rb * NI + jb] = ctab[st] * sB[rb * NI + jb] + dt * ac;
        }
        __syncthreads();
    }

    const float btab[6] = {35.f / 384.f, 0.f, 500.f / 1113.f, 125.f / 192.f,
                           -2187.f / 6784.f, 11.f / 84.f};
    for (int e = tid; e < NS * NS; e += 256) {
        float acc = 0.f;
        for (int i2 = 0; i2 < 6; ++i2) acc += btab[i2] * Ka[i2][e];
        const float m = dt * acc + (((e / NS) == (e % NS)) ? 1.f : 0.f);
        ws[WS_M + e] = m;
        // pair-packed copy for phase3's pk-FMA path
        const int row = e / NS, col = e % NS;
        ws[WS_MP + (row >> 2) * 128 + ((row >> 1) & 1) * 64 + col * 2 + (row & 1)] = m;
        Pq[0][e] = m;
        Ms[e] = m;  // live copy of M for the F build
    }
    for (int e = tid; e < NS * NI; e += 256) {
        float ap = 0.f, aq = 0.f;
        for (int i2 = 0; i2 < 6; ++i2) {
            ap += btab[i2] * Kb[i2][e];
            aq += btab[i2] * Kc[i2][e];
        }
        const float P = dt * ap, Q = dt * aq;
        ws[WS_N0 + e] = P - Q;  // coefficient of u_n
        ws[WS_N1 + e] = Q;      // coefficient of u_{n+1}
        Sb[e] = P - Q;          // N0'
        Sc[e] = Q;              // N1'
    }
    __syncthreads();

    // ML = M^64 via 6 squarings; capture M^8 into Sa (dead after RK stages).
    int cur = 0;
    for (int itq = 0; itq < 6; ++itq) {
        const int j = tid & 31, ig = tid >> 5;
        for (int r = 0; r < 4; ++r) {
            const int row = ig + 8 * r;
            float acc = 0.f;
            for (int k = 0; k < NS; ++k) acc += Pq[cur][row * NS + k] * Pq[cur][k * NS + j];
            Pq[cur ^ 1][row * NS + j] = acc;
        }
        __syncthreads();
        cur ^= 1;
        if (itq == 2)
            for (int e = tid; e < NS * NS; e += 256) Sa[e] = Pq[cur][e];  // M^8
    }
    for (int e = tid; e < NS * NS; e += 256) ws[WS_ML + e] = Pq[cur][e];

    // ---- F build, log depth. chainbuf pages alias Ka (dead). ----
    // cb stays in plain row-major element order; only ws[WS_F] output is packed.
    float* cb = &Ka[0][0];
    const int rr = tid >> 3, mm = tid & 7;
    const int fi = fidx(rr, mm);

    float mrow[NS], m8row[NS];
#pragma unroll
    for (int kk = 0; kk < NS; ++kk) { mrow[kk] = Ms[rr * NS + kk]; m8row[kk] = Sa[rr * NS + kk]; }

    // H = N0' + M N1'  -> F_63 (seed 0)
    {
        float acc = 0.f;
#pragma unroll
        for (int kk = 0; kk < NS; ++kk) acc += mrow[kk] * Sc[kk * NI + mm];
        const float h = Sb[tid] + acc;
        cb[tid] = h;
        ws[WS_F + 63 * (NS * NI) + fi] = h;
    }
    __syncthreads();
    // seeds S_i = M^8 S_{i-1} -> F_{63-8i}
    for (int i = 1; i < 8; ++i) {
        float acc = 0.f;
#pragma unroll
        for (int kk = 0; kk < NS; ++kk) acc += m8row[kk] * cb[(i - 1) * 256 + kk * NI + mm];
        cb[i * 256 + tid] = acc;
        ws[WS_F + (63 - 8 * i) * (NS * NI) + fi] = acc;
        __syncthreads();
    }
    // 7 parallel steps: advance all 8 chains by M
    int pp = 0;
    for (int k = 1; k < 8; ++k) {
        float acc[8];
#pragma unroll
        for (int i = 0; i < 8; ++i) {
            float a = 0.f;
#pragma unroll
            for (int kk = 0; kk < NS; ++kk) a += mrow[kk] * cb[pp * 2048 + i * 256 + kk * NI + mm];
            acc[i] = a;
        }
#pragma unroll
        for (int i = 0; i < 8; ++i) {
            cb[(pp ^ 1) * 2048 + i * 256 + tid] = acc[i];
            ws[WS_F + (63 - 8 * i - k) * (NS * NI) + fi] = acc[i];
        }
        __syncthreads();
        pp ^= 1;
    }
    ws[WS_F + 64 * (NS * NI) + fi] = Sc[tid];  // F_64 = N1'
}

// ---------------------------------------------------------------------------
// Phase 1 (GEMM form, v4-pk): v[b][c] = sum_{j=0..64} F_j u_{t0+j}
// WS_F is pre-packed by k_pre -> staging is a LINEAR 64 KB copy (coalesced,
// conflict-free). Reads: float4 slot (sl^s8) -> 8 distinct bank groups.
// Inner loop is 16 pk-FMA per j (was 64 scalar FMA).
// ---------------------------------------------------------------------------
__global__ __launch_bounds__(256, 2) void k_phase1(const float* __restrict__ u,
                                                   float* __restrict__ ws) {
    __shared__ float4 sF[64 * 64];  // 65536 B

    const int tid = threadIdx.x;
    const float4* Fg = (const float4*)(ws + WS_F);
    for (int idx = tid; idx < 64 * 64; idx += 256) sF[idx] = Fg[idx];
    __syncthreads();

    const int task = blockIdx.x * 4 + (tid >> 6);
    const int c = task % (NCHUNKS - 1), g = task / (NCHUNKS - 1);
    const int l = tid & 63;
    const int beta = l >> 3, s8 = l & 7;
    const int b = g * 8 + beta;
    const int t0 = c * LCH;
    const float* ub = u + ((size_t)b * TT + t0) * NI;

    float4 ua = ld4(ub), uc = ld4(ub + 4);
    float2 a01a = make_float2(0.f, 0.f), a01b = make_float2(0.f, 0.f);
    float2 a23a = make_float2(0.f, 0.f), a23b = make_float2(0.f, 0.f);

    const float4* fb = &sF[s8 << 3];

#pragma unroll 4
    for (int j = 0; j < 64; ++j) {
        // prefetch next u (always valid: t0+64 <= 4032)
        const float4 na = ld4(ub + (j + 1) * NI);
        const float4 nb = ld4(ub + (j + 1) * NI + 4);
        const float4* fj = fb + (j << 6);
        const float4 f0 = fj[0 ^ s8], f1 = fj[1 ^ s8], f2 = fj[2 ^ s8], f3 = fj[3 ^ s8];
        const float4 g0 = fj[4 ^ s8], g1 = fj[5 ^ s8], g2 = fj[6 ^ s8], g3 = fj[7 ^ s8];
        fma2(a01a, make_float2(f0.x, f0.y), ua.x); fma2(a01a, make_float2(f0.z, f0.w), ua.y);
        fma2(a01b, make_float2(f1.x, f1.y), ua.z); fma2(a01b, make_float2(f1.z, f1.w), ua.w);
        fma2(a01a, make_float2(f2.x, f2.y), uc.x); fma2(a01a, make_float2(f2.z, f2.w), uc.y);
        fma2(a01b, make_float2(f3.x, f3.y), uc.z); fma2(a01b, make_float2(f3.z, f3.w), uc.w);
        fma2(a23a, make_float2(g0.x, g0.y), ua.x); fma2(a23a, make_float2(g0.z, g0.w), ua.y);
        fma2(a23b, make_float2(g1.x, g1.y), ua.z); fma2(a23b, make_float2(g1.z, g1.w), ua.w);
        fma2(a23a, make_float2(g2.x, g2.y), uc.x); fma2(a23a, make_float2(g2.z, g2.w), uc.y);
        fma2(a23b, make_float2(g3.x, g3.y), uc.z); fma2(a23b, make_float2(g3.z, g3.w), uc.w);
        ua = na; uc = nb;
    }

    // j = 64 tail: F_64 (packed) from global, ua/uc hold u[t0+64]
    {
        const float4* ftb = (const float4*)(ws + WS_F + 64 * (NS * NI)) + (s8 << 3);
        const float4 f0 = ftb[0 ^ s8], f1 = ftb[1 ^ s8], f2 = ftb[2 ^ s8], f3 = ftb[3 ^ s8];
        const float4 g0 = ftb[4 ^ s8], g1 = ftb[5 ^ s8], g2 = ftb[6 ^ s8], g3 = ftb[7 ^ s8];
        fma2(a01a, make_float2(f0.x, f0.y), ua.x); fma2(a01a, make_float2(f0.z, f0.w), ua.y);
        fma2(a01b, make_float2(f1.x, f1.y), ua.z); fma2(a01b, make_float2(f1.z, f1.w), ua.w);
        fma2(a01a, make_float2(f2.x, f2.y), uc.x); fma2(a01a, make_float2(f2.z, f2.w), uc.y);
        fma2(a01b, make_float2(f3.x, f3.y), uc.z); fma2(a01b, make_float2(f3.z, f3.w), uc.w);
        fma2(a23a, make_float2(g0.x, g0.y), ua.x); fma2(a23a, make_float2(g0.z, g0.w), ua.y);
        fma2(a23b, make_float2(g1.x, g1.y), ua.z); fma2(a23b, make_float2(g1.z, g1.w), ua.w);
        fma2(a23a, make_float2(g2.x, g2.y), uc.x); fma2(a23a, make_float2(g2.z, g2.w), uc.y);
        fma2(a23b, make_float2(g3.x, g3.y), uc.z); fma2(a23b, make_float2(g3.z, g3.w), uc.w);
    }

    *(float4*)(ws + WS_V + ((size_t)b * NCHUNKS + c) * NS + 4 * s8) =
        make_float4(a01a.x + a01b.x, a01a.y + a01b.y, a23a.x + a23b.x, a23a.y + a23b.y);
}

// ---------------------------------------------------------------------------
// Phase 2: propagate chunk start states. One wave per batch.
// ---------------------------------------------------------------------------
__global__ __launch_bounds__(64) void k_phase2(const float* __restrict__ x0,
                                               float* __restrict__ ws) {
    const float* ML = ws + WS_ML;
    const float* v = ws + WS_V;
    float* sst = ws + WS_S;
    const int b = blockIdx.x;
    const int l = threadIdx.x, i = l & 31, h = l >> 5;

    float mlr[16];
#pragma unroll
    for (int jj = 0; jj < 16; ++jj) mlr[jj] = ML[i * NS + 16 * h + jj];

    float x = x0[b * NS + i];
    for (int c = 0; c < NCHUNKS; ++c) {
        if (h == 0) sst[((size_t)b * NCHUNKS + c) * NS + i] = x;
        if (c == NCHUNKS - 1) break;
        float p = 0.f;
#pragma unroll
        for (int jj = 0; jj < 16; ++jj) p += mlr[jj] * __shfl(x, 16 * h + jj, 64);
        p += __shfl_xor(p, 32, 64);
        x = p + v[((size_t)b * NCHUNKS + c) * NS + i];
    }
}

// ---------------------------------------------------------------------------
// Phase 3 (v6-pk): round-6 111-us structure (8 batches/wave, LDS b128
// x-exchange, 2-ahead u prefetch, (64,1), wave-synchronous lgkmcnt skeleton)
// with the inner math pair-packed: M rows cached as (row r, row r+1) float2
// pairs from WS_MP -> M*x is 64 pk-FMA (was 128), N 32 pk, y ~20 pk.
// Same register footprint; ~45% fewer VALU insts/step if v_pk_fma_f32 lands.
// Do NOT cap VGPRs ((64,3) -> spill catastrophe, round 5); bulk exchange via
// LDS b128, never 32 shuffles (round 7); don't split columns (round 8).
// ---------------------------------------------------------------------------
__global__ __launch_bounds__(64, 1) void k_phase3(const float* __restrict__ u,
                                                  float* __restrict__ ws,
                                                  float* __restrict__ out,
                                                  const float* __restrict__ Cc,
                                                  const float* __restrict__ Dd) {
    const float* MP = ws + WS_MP;
    const float* N0 = ws + WS_N0;
    const float* N1 = ws + WS_N1;

    const int task = blockIdx.x;
    const int c = task % NCHUNKS, g = task / NCHUNKS;
    const int l = threadIdx.x;
    const int beta = l >> 3, s8 = l & 7;
    const int b = g * 8 + beta;

    // M rows 4*s8..4*s8+3 as row-pairs: mp01[k2] = (M[r0][2k2],M[r1][2k2],
    // M[r0][2k2+1],M[r1][2k2+1]); mp23 likewise for rows r2,r3. 128 VGPRs.
    float4 mp01[16], mp23[16];
#pragma unroll
    for (int k2 = 0; k2 < 16; ++k2) {
        mp01[k2] = ld4(MP + s8 * 128 + 4 * k2);
        mp23[k2] = ld4(MP + s8 * 128 + 64 + 4 * k2);
    }

    float2 n0p01[8], n0p23[8], n1p01[8], n1p23[8];
#pragma unroll
    for (int i = 0; i < 8; ++i) {
        n0p01[i] = make_float2(N0[(4 * s8 + 0) * NI + i], N0[(4 * s8 + 1) * NI + i]);
        n0p23[i] = make_float2(N0[(4 * s8 + 2) * NI + i], N0[(4 * s8 + 3) * NI + i]);
        n1p01[i] = make_float2(N1[(4 * s8 + 0) * NI + i], N1[(4 * s8 + 1) * NI + i]);
        n1p23[i] = make_float2(N1[(4 * s8 + 2) * NI + i], N1[(4 * s8 + 3) * NI + i]);
    }

    float4 cq[8];
#pragma unroll
    for (int jj = 0; jj < 8; ++jj) cq[jj] = ld4(Cc + s8 * NS + 4 * jj);
    const float4 dq0 = ld4(Dd + s8 * NI);
    const float4 dq1 = ld4(Dd + s8 * NI + 4);

    // per-wave x buffer, double-buffered; row stride 9 float4 (conflict-free).
    __shared__ float4 xb[2][8 * 9];

    const int t0 = c * LCH;
    const float* ub = u + (size_t)b * TT * NI;
    float4 u0a = ld4(ub + t0 * NI), u0b = ld4(ub + t0 * NI + 4);
    float4 u1a = ld4(ub + (t0 + 1) * NI), u1b = ld4(ub + (t0 + 1) * NI + 4);

    float4 mine = ld4(ws + WS_S + ((size_t)b * NCHUNKS + c) * NS + 4 * s8);
    xb[0][beta * 9 + s8] = mine;
    asm volatile("s_waitcnt lgkmcnt(0)" ::: "memory");
    __builtin_amdgcn_sched_barrier(0);

    float* xp = out + ((size_t)b * TT + t0) * NS + 4 * s8;
    float* yp = out + (size_t)BATCH * TT * NS + ((size_t)b * TT + t0) * NO + s8;

    int cur = 0;
    for (int js = 0; js < LCH; ++js) {
        const int t = t0 + js;
        float4 xq[8];
#pragma unroll
        for (int jj = 0; jj < 8; ++jj) xq[jj] = xb[cur][beta * 9 + jj];

        // prefetch u[t+2] (index-clamped; dead values never consumed)
        const int tp = (t + 2 < TT - 1) ? (t + 2) : (TT - 1);
        const float4 u2a = ld4(ub + tp * NI);
        const float4 u2b = ld4(ub + tp * NI + 4);

        // store xs[b][t][4*s8 .. 4*s8+3]
        *(float4*)xp = mine;

        // y[b][t][s8] = C x + D u, packed pairs
        float2 y2 = make_float2(0.f, 0.f);
#pragma unroll
        for (int jj = 0; jj < 8; ++jj) {
            fma22(y2, make_float2(cq[jj].x, cq[jj].y), make_float2(xq[jj].x, xq[jj].y));
            fma22(y2, make_float2(cq[jj].z, cq[jj].w), make_float2(xq[jj].z, xq[jj].w));
        }
        fma22(y2, make_float2(dq0.x, dq0.y), make_float2(u0a.x, u0a.y));
        fma22(y2, make_float2(dq0.z, dq0.w), make_float2(u0a.z, u0a.w));
        fma22(y2, make_float2(dq1.x, dq1.y), make_float2(u0b.x, u0b.y));
        fma22(y2, make_float2(dq1.z, dq1.w), make_float2(u0b.z, u0b.w));
        *yp = y2.x + y2.y;

        if (js < LCH - 1) {
            float2 w01a = make_float2(0.f, 0.f), w01b = make_float2(0.f, 0.f);
            float2 w23a = make_float2(0.f, 0.f), w23b = make_float2(0.f, 0.f);
            // N terms (u0 via N0-pairs, u1 via N1-pairs)
            fma2(w01a, n0p01[0], u0a.x); fma2(w23a, n0p23[0], u0a.x);
            fma2(w01b, n0p01[1], u0a.y); fma2(w23b, n0p23[1], u0a.y);
            fma2(w01a, n0p01[2], u0a.z); fma2(w23a, n0p23[2], u0a.z);
            fma2(w01b, n0p01[3], u0a.w); fma2(w23b, n0p23[3], u0a.w);
            fma2(w01a, n0p01[4], u0b.x); fma2(w23a, n0p23[4], u0b.x);
            fma2(w01b, n0p01[5], u0b.y); fma2(w23b, n0p23[5], u0b.y);
            fma2(w01a, n0p01[6], u0b.z); fma2(w23a, n0p23[6], u0b.z);
            fma2(w01b, n0p01[7], u0b.w); fma2(w23b, n0p23[7], u0b.w);
            fma2(w01a, n1p01[0], u1a.x); fma2(w23a, n1p23[0], u1a.x);
            fma2(w01b, n1p01[1], u1a.y); fma2(w23b, n1p23[1], u1a.y);
            fma2(w01a, n1p01[2], u1a.z); fma2(w23a, n1p23[2], u1a.z);
            fma2(w01b, n1p01[3], u1a.w); fma2(w23b, n1p23[3], u1a.w);
            fma2(w01a, n1p01[4], u1b.x); fma2(w23a, n1p23[4], u1b.x);
            fma2(w01b, n1p01[5], u1b.y); fma2(w23b, n1p23[5], u1b.y);
            fma2(w01a, n1p01[6], u1b.z); fma2(w23a, n1p23[6], u1b.z);
            fma2(w01b, n1p01[7], u1b.w); fma2(w23b, n1p23[7], u1b.w);
            // M*x: 64 pk-FMA
#pragma unroll
            for (int jj = 0; jj < 8; ++jj) {
                const float4 xv = xq[jj];
                const float4 ma = mp01[2 * jj], mb = mp01[2 * jj + 1];
                const float4 pa = mp23[2 * jj], pb = mp23[2 * jj + 1];
                fma2(w01a, make_float2(ma.x, ma.y), xv.x);
                fma2(w01a, make_float2(ma.z, ma.w), xv.y);
                fma2(w01b, make_float2(mb.x, mb.y), xv.z);
                fma2(w01b, make_float2(mb.z, mb.w), xv.w);
                fma2(w23a, make_float2(pa.x, pa.y), xv.x);
                fma2(w23a, make_float2(pa.z, pa.w), xv.y);
                fma2(w23b, make_float2(pb.x, pb.y), xv.z);
                fma2(w23b, make_float2(pb.z, pb.w), xv.w);
            }
            mine = make_float4(w01a.x + w01b.x, w01a.y + w01b.y,
                               w23a.x + w23b.x, w23a.y + w23b.y);
            xb[cur ^ 1][beta * 9 + s8] = mine;
            u0a = u1a; u0b = u1b;
            u1a = u2a; u1b = u2b;
        }
        asm volatile("s_waitcnt lgkmcnt(0)" ::: "memory");
        __builtin_amdgcn_sched_barrier(0);
        cur ^= 1;
        xp += NS;
        yp += NO;
    }
}

extern "C" void kernel_launch(void* const* d_in, const int* in_sizes, int n_in,
                              void* d_out, int out_size, void* d_ws, size_t ws_size,
                              hipStream_t stream) {
    const float* t = (const float*)d_in[0];
    const float* u = (const float*)d_in[1];
    const float* x0 = (const float*)d_in[2];
    const float* A = (const float*)d_in[3];
    const float* B = (const float*)d_in[4];
    const float* C = (const float*)d_in[5];
    const float* D = (const float*)d_in[6];
    float* out = (float*)d_out;
    float* ws = (float*)d_ws;

    k_pre<<<dim3(1), dim3(256), 0, stream>>>(t, A, B, ws);
    k_phase1<<<dim3(8 * (NCHUNKS - 1)), dim3(256), 0, stream>>>(u, ws);
    k_phase2<<<dim3(BATCH), dim3(64), 0, stream>>>(x0, ws);
    k_phase3<<<dim3(32 * NCHUNKS), dim3(64), 0, stream>>>(u, ws, out, C, D);
}